// Round 5
// baseline (642.368 us; speedup 1.0000x reference)
//
#include <hip/hip_runtime.h>

#define NROWS 4096
#define DK    1024
#define DLAT  32768
#define NUNIT (NROWS * 3)

typedef float  f32x4  __attribute__((ext_vector_type(4)));
typedef short  bf16x8 __attribute__((ext_vector_type(8)));
typedef unsigned short u16;

// Path A (big ws): d_ws layout = Wb[64M) Ab[64M,72M) approx[72M,328M); output direct to d_out.
// Path B (small ws, fallback = R4): approx/Wb/Ab inside d_out, pairs in d_ws, zero_scatter pass.
#define WSA_WB   0
#define WSA_AB   ((size_t)DLAT * DK * 2)
#define WSA_APX  (WSA_AB + (size_t)NROWS * DK * 2)
#define WSA_NEED (WSA_APX + (size_t)NROWS * DLAT * 2)

#define APX_BYTES ((size_t)NROWS * DLAT * 2)
#define WB_OFF  APX_BYTES
#define AB_OFF  (WB_OFF + (size_t)DLAT * DK * 2)

#define BCAP 160
#define QINV 2.44140625e-4f
#define EQ2  82      // 2*E in q units (E = 0.01)
#define NPAIR 224    // 32+64+128

__device__ __forceinline__ u16 f2bf(float f) {
    unsigned u = __float_as_uint(f);
    return (u16)((u + 0x7FFF + ((u >> 16) & 1)) >> 16);
}

// ---------------- P0: fp32 -> bf16 copies of W and A ----------------
__global__ __launch_bounds__(256) void convert_bf16(
    const float* __restrict__ W, const float* __restrict__ A,
    u16* __restrict__ Wb, u16* __restrict__ Ab)
{
    const size_t NW = (size_t)DLAT * DK / 4;
    const size_t NA = (size_t)NROWS * DK / 4;
    size_t i = (size_t)blockIdx.x * 256 + threadIdx.x;
    const size_t stride = (size_t)gridDim.x * 256;
    for (; i < NW + NA; i += stride) {
        const float4 v = (i < NW) ? ((const float4*)W)[i] : ((const float4*)A)[i - NW];
        ushort4 o;
        o.x = f2bf(v.x); o.y = f2bf(v.y); o.z = f2bf(v.z); o.w = f2bf(v.w);
        if (i < NW) ((ushort4*)Wb)[i] = o; else ((ushort4*)Ab)[i - NW] = o;
    }
}

// ---------------- P1: 256x256 8-phase bf16 MFMA GEMM -> approx (u16 fixed point) ----------------
#define GLDS(src, dst) __builtin_amdgcn_global_load_lds( \
    (const __attribute__((address_space(1))) void*)(src), \
    (__attribute__((address_space(3))) void*)(dst), 16, 0, 0)

__device__ __forceinline__ void ld_afrag(bf16x8 af[4][2], const u16* sbuf,
                                         int qm, int wm, int lr, int lk, int l7) {
#pragma unroll
    for (int mf = 0; mf < 4; ++mf)
#pragma unroll
        for (int kk = 0; kk < 2; ++kk)
            af[mf][kk] = *(const bf16x8*)&sbuf[(qm * 128 + wm * 64 + mf * 16 + lr) * 64
                                               + (((kk * 4 + lk) ^ l7) * 8)];
}
__device__ __forceinline__ void ld_bfrag(bf16x8 bfr[2][2], const u16* sbuf,
                                         int qn, int wn, int lr, int lk, int l7) {
#pragma unroll
    for (int nf = 0; nf < 2; ++nf)
#pragma unroll
        for (int kk = 0; kk < 2; ++kk)
            bfr[nf][kk] = *(const bf16x8*)&sbuf[(qn * 128 + wn * 32 + nf * 16 + lr) * 64
                                                + (((kk * 4 + lk) ^ l7) * 8)];
}
__device__ __forceinline__ void mma_quad(f32x4 acc[8][4], const bf16x8 af[4][2],
                                         const bf16x8 bfr[2][2], int qm, int qn) {
#pragma unroll
    for (int mf = 0; mf < 4; ++mf)
#pragma unroll
        for (int nf = 0; nf < 2; ++nf)
#pragma unroll
            for (int kk = 0; kk < 2; ++kk)
                acc[qm * 4 + mf][qn * 2 + nf] = __builtin_amdgcn_mfma_f32_16x16x32_bf16(
                    af[mf][kk], bfr[nf][kk], acc[qm * 4 + mf][qn * 2 + nf], 0, 0, 0);
}

__global__ __launch_bounds__(512, 2) void gemm8(
    const u16* __restrict__ Ab, const u16* __restrict__ Wb,
    const float* __restrict__ bias, u16* __restrict__ approx,
    float* __restrict__ Zout)   // Zout != nullptr: zero-fill this block's output tile
{
    __shared__ __align__(16) u16 sm[4][256 * 64];   // A0,A1,B0,B1 = 128 KB
    u16* sAb[2] = { sm[0], sm[1] };
    u16* sBb[2] = { sm[2], sm[3] };

    const int tid = threadIdx.x;
    const int w = tid >> 6, l = tid & 63;
    const int wm = w >> 2, wn = w & 3;
    const int lr = l & 15, lk = l >> 4, l7 = l & 7;

    const int bid = blockIdx.x;
    const int swz = (bid & 7) * 256 + (bid >> 3);   // 2048 % 8 == 0: bijective
    const int rb = swz >> 7, cb = swz & 127;

    const int sub = l >> 3;
    const int ss  = (l & 7) ^ sub;                  // source slot = lds slot ^ (qrow&7)
    const u16* gA[4]; const u16* gB[4];
    u16* dA[2][4]; u16* dB[2][4];
#pragma unroll
    for (int c = 0; c < 4; ++c) {
        const int q  = c * 64 + w * 8 + sub;
        const int mA = ((q >> 6) & 1) * 128 + (q >> 7) * 64 + (q & 63);
        const int nB = ((q >> 5) & 3) * 64  + (q >> 7) * 32 + (q & 31);
        gA[c] = Ab + (size_t)(rb * 256 + mA) * DK + ss * 8;
        gB[c] = Wb + (size_t)(cb * 256 + nB) * DK + ss * 8;
#pragma unroll
        for (int bb = 0; bb < 2; ++bb) {
            dA[bb][c] = sAb[bb] + (c * 64 + w * 8) * 64;
            dB[bb][c] = sBb[bb] + (c * 64 + w * 8) * 64;
        }
    }

    f32x4 acc[8][4];
#pragma unroll
    for (int i = 0; i < 8; ++i)
#pragma unroll
        for (int j = 0; j < 4; ++j) acc[i][j] = (f32x4){0.f, 0.f, 0.f, 0.f};

    GLDS(gA[0], dA[0][0]); GLDS(gA[1], dA[0][1]);
    GLDS(gB[0], dB[0][0]); GLDS(gB[1], dB[0][1]);
    GLDS(gB[2], dB[0][2]); GLDS(gB[3], dB[0][3]);
    GLDS(gA[2], dA[0][2]); GLDS(gA[3], dA[0][3]);

    bf16x8 af[4][2], bf0[2][2], bf1[2][2];

    for (int t = 0; t < 15; ++t) {
        const int b = t & 1;
        const u16* cA = sAb[b]; const u16* cB = sBb[b];
        const int ko = (t + 1) * 64;
        asm volatile("s_waitcnt vmcnt(4)" ::: "memory");
        __builtin_amdgcn_s_barrier();
        __builtin_amdgcn_sched_barrier(0);
        ld_afrag(af, cA, 0, wm, lr, lk, l7);
        ld_bfrag(bf0, cB, 0, wn, lr, lk, l7);
        GLDS(gA[0] + ko, dA[b ^ 1][0]); GLDS(gA[1] + ko, dA[b ^ 1][1]);
        __builtin_amdgcn_s_setprio(1);
        mma_quad(acc, af, bf0, 0, 0);
        __builtin_amdgcn_s_setprio(0);
        asm volatile("s_waitcnt vmcnt(4)" ::: "memory");
        __builtin_amdgcn_s_barrier();
        __builtin_amdgcn_sched_barrier(0);
        ld_bfrag(bf1, cB, 1, wn, lr, lk, l7);
        GLDS(gB[0] + ko, dB[b ^ 1][0]); GLDS(gB[1] + ko, dB[b ^ 1][1]);
        __builtin_amdgcn_s_setprio(1);
        mma_quad(acc, af, bf1, 0, 1);
        __builtin_amdgcn_s_setprio(0);
        asm volatile("s_waitcnt vmcnt(4)" ::: "memory");
        __builtin_amdgcn_s_barrier();
        __builtin_amdgcn_sched_barrier(0);
        ld_afrag(af, cA, 1, wm, lr, lk, l7);
        GLDS(gB[2] + ko, dB[b ^ 1][2]); GLDS(gB[3] + ko, dB[b ^ 1][3]);
        __builtin_amdgcn_s_setprio(1);
        mma_quad(acc, af, bf1, 1, 1);
        __builtin_amdgcn_s_setprio(0);
        GLDS(gA[2] + ko, dA[b ^ 1][2]); GLDS(gA[3] + ko, dA[b ^ 1][3]);
        __builtin_amdgcn_s_setprio(1);
        mma_quad(acc, af, bf0, 1, 0);
        __builtin_amdgcn_s_setprio(0);
    }
    {
        const u16* cA = sAb[1]; const u16* cB = sBb[1];
        asm volatile("s_waitcnt vmcnt(4)" ::: "memory");
        __builtin_amdgcn_s_barrier();
        __builtin_amdgcn_sched_barrier(0);
        ld_afrag(af, cA, 0, wm, lr, lk, l7);
        ld_bfrag(bf0, cB, 0, wn, lr, lk, l7);
        __builtin_amdgcn_s_setprio(1);
        mma_quad(acc, af, bf0, 0, 0);
        __builtin_amdgcn_s_setprio(0);
        asm volatile("s_waitcnt vmcnt(2)" ::: "memory");
        __builtin_amdgcn_s_barrier();
        __builtin_amdgcn_sched_barrier(0);
        ld_bfrag(bf1, cB, 1, wn, lr, lk, l7);
        __builtin_amdgcn_s_setprio(1);
        mma_quad(acc, af, bf1, 0, 1);
        __builtin_amdgcn_s_setprio(0);
        asm volatile("s_waitcnt vmcnt(0)" ::: "memory");
        __builtin_amdgcn_s_barrier();
        __builtin_amdgcn_sched_barrier(0);
        ld_afrag(af, cA, 1, wm, lr, lk, l7);
        __builtin_amdgcn_s_setprio(1);
        mma_quad(acc, af, bf1, 1, 1);
        mma_quad(acc, af, bf0, 1, 0);
        __builtin_amdgcn_s_setprio(0);
    }

    // zero-fill this block's 256x256 output tile (stores kept OUT of the
    // vmcnt-counted K-loop; overlaps with epilogue VALU work)
    if (Zout) {
        const float4 z4 = make_float4(0.f, 0.f, 0.f, 0.f);
#pragma unroll
        for (int it = 0; it < 32; ++it) {
            const int idx = it * 512 + tid;
            const int r = idx >> 6, c = idx & 63;
            ((float4*)(Zout + (size_t)(rb * 256 + r) * DLAT))[cb * 64 + c] = z4;
        }
    }

    const int r0 = rb * 256 + wm * 128;
    const int c0 = cb * 256 + wn * 64;
#pragma unroll
    for (int jn = 0; jn < 4; ++jn) {
        const int col = c0 + (jn >> 1) * 32 + (jn & 1) * 16 + lr;
        const float bv = bias[col];
#pragma unroll
        for (int i = 0; i < 8; ++i) {
            const int mrow = r0 + (i >> 2) * 64 + (i & 3) * 16 + lk * 4;
#pragma unroll
            for (int r = 0; r < 4; ++r) {
                const float pre = acc[i][jn][r] + bv;
                int q = __float2int_rn(pre * 4096.f) + 32768;
                q = min(max(q, 0), 65535);
                approx[(size_t)(mrow + r) * DLAT + col] = (u16)q;
            }
        }
    }
}

// ---------------- P2: histogram select + exact rescore + finalize ----------------
// Zd != nullptr: scatter final values directly into pre-zeroed output.
// Zd == nullptr: emit (val,col) pairs to pv/pc (fallback path).
__global__ __launch_bounds__(256) void select_rescore_final(
    const u16* __restrict__ apx, const float* __restrict__ h2,
    const float* __restrict__ W, const float* __restrict__ bias,
    float* __restrict__ pv, int* __restrict__ pc, float* __restrict__ Zd)
{
    __shared__ int hist[4096];
    __shared__ __align__(16) float sAr[DK];
    __shared__ int wsum[4];
    __shared__ int s_B, s_ns, s_nb;
    __shared__ u16 bcol[BCAP];
    __shared__ float bpre[BCAP];

    const int tid = threadIdx.x, lane = tid & 63, wv = tid >> 6;
    const int u = blockIdx.x;
    const int row = u / 3, lvl = u - 3 * row;
    const int LSTART[3] = {0, 2048, 8192};
    const int LN[3]     = {2048, 6144, 24576};
    const int LK_[3]    = {32, 64, 128};
    const int PB_[3]    = {0, 32, 96};
    const int start = LSTART[lvl], n = LN[lvl], k = LK_[lvl], pbase = PB_[lvl];

    for (int i = tid; i < DK / 4; i += 256)
        ((float4*)sAr)[i] = ((const float4*)(h2 + (size_t)row * DK))[i];
#pragma unroll
    for (int i = 0; i < 16; ++i) hist[tid * 16 + i] = 0;
    if (tid == 0) { s_ns = 0; s_nb = 0; }
    __syncthreads();

    const uint4* base = (const uint4*)(apx + (size_t)row * DLAT + start);
    const int n8 = n >> 3;
    for (int i = tid; i < n8; i += 256) {
        const uint4 v = base[i];
        atomicAdd(&hist[(v.x & 0xFFFF) >> 4], 1);
        atomicAdd(&hist[(v.x >> 16) >> 4], 1);
        atomicAdd(&hist[(v.y & 0xFFFF) >> 4], 1);
        atomicAdd(&hist[(v.y >> 16) >> 4], 1);
        atomicAdd(&hist[(v.z & 0xFFFF) >> 4], 1);
        atomicAdd(&hist[(v.z >> 16) >> 4], 1);
        atomicAdd(&hist[(v.w & 0xFFFF) >> 4], 1);
        atomicAdd(&hist[(v.w >> 16) >> 4], 1);
    }
    __syncthreads();

    const int b0 = 4095 - 16 * tid;
    int part = 0;
#pragma unroll
    for (int i = 0; i < 16; ++i) part += hist[b0 - i];
    int incl = part;
#pragma unroll
    for (int s = 1; s < 64; s <<= 1) {
        const int t = __shfl_up(incl, s);
        if (lane >= s) incl += t;
    }
    if (lane == 63) wsum[wv] = incl;
    __syncthreads();
    int woff = 0;
    for (int j = 0; j < wv; ++j) woff += wsum[j];
    const int above = woff + incl - part;
    if (above < k && above + part >= k) {
        int run = above, B = -1;
        for (int i = 0; i < 16; ++i) {
            run += hist[b0 - i];
            if (run >= k) { B = b0 - i; break; }
        }
        s_B = B;
    }
    __syncthreads();

    const int qsure = s_B * 16 + 16 + EQ2;
    const int qband = s_B * 16 - EQ2;
    const size_t obase = (size_t)row * NPAIR + pbase;
    const size_t zbase = (size_t)row * DLAT;

    for (int i = tid; i < n8; i += 256) {
        const uint4 v = base[i];
        const int col0 = start + i * 8;
        unsigned qs[8] = { v.x & 0xFFFF, v.x >> 16, v.y & 0xFFFF, v.y >> 16,
                           v.z & 0xFFFF, v.z >> 16, v.w & 0xFFFF, v.w >> 16 };
#pragma unroll
        for (int j = 0; j < 8; ++j) {
            const int q = (int)qs[j];
            if (q >= qsure) {
                const int p = atomicAdd(&s_ns, 1);
                if (p < k) {
                    const float a = (q - 32768) * QINV;
                    const float val = fmaxf(a, 0.f) + (a > 1.f ? 1.f : 0.f);
                    if (Zd) Zd[zbase + col0 + j] = val;
                    else { pv[obase + p] = val; pc[obase + p] = col0 + j; }
                }
            } else if (q >= qband) {
                const int p = atomicAdd(&s_nb, 1);
                if (p < BCAP) bcol[p] = (u16)(col0 + j);
            }
        }
    }
    __syncthreads();
    const int m  = min(s_ns, k);
    const int bc = min(s_nb, BCAP);

    for (int c = wv; c < bc; c += 4) {
        const int col = bcol[c];
        const float* wrow = W + (size_t)col * DK;
        float p = 0.f;
#pragma unroll
        for (int j = 0; j < 4; ++j) {
            const float4 w4 = ((const float4*)wrow)[j * 64 + lane];
            const float4 a4 = ((const float4*)sAr)[j * 64 + lane];
            p = fmaf(w4.x, a4.x, p); p = fmaf(w4.y, a4.y, p);
            p = fmaf(w4.z, a4.z, p); p = fmaf(w4.w, a4.w, p);
        }
#pragma unroll
        for (int s = 32; s; s >>= 1) p += __shfl_xor(p, s);
        if (lane == 0) bpre[c] = p + bias[col];
    }
    __syncthreads();

    const int need = k - m;
    for (int c = tid; c < bc; c += 256) {
        const float pc_ = bpre[c];
        const int colc = bcol[c];
        int rank = 0;
        for (int d = 0; d < bc; ++d) {
            const float pd = bpre[d];
            rank += (pd > pc_) || (pd == pc_ && bcol[d] < colc);
        }
        if (rank < need) {
            const float z = fmaxf(pc_, 0.f) + (pc_ > 1.f ? 1.f : 0.f);
            if (Zd) Zd[zbase + colc] = z;
            else { pv[obase + m + rank] = z; pc[obase + m + rank] = colc; }
        }
    }
}

// ---------------- P3 (fallback only): zero row + scatter its pairs ----------------
__global__ __launch_bounds__(256) void zero_scatter(
    const float* __restrict__ pv, const int* __restrict__ pc, float* __restrict__ Z)
{
    const int row = blockIdx.x, tid = threadIdx.x;
    float4* zr = (float4*)(Z + (size_t)row * DLAT);
    const float4 z4 = make_float4(0.f, 0.f, 0.f, 0.f);
#pragma unroll
    for (int i = 0; i < 32; ++i) zr[tid + i * 256] = z4;
    __syncthreads();
    if (tid < NPAIR) {
        const float v = pv[(size_t)row * NPAIR + tid];
        const int col = pc[(size_t)row * NPAIR + tid];
        Z[(size_t)row * DLAT + col] = v;
    }
}

extern "C" void kernel_launch(void* const* d_in, const int* in_sizes, int n_in,
                              void* d_out, int out_size, void* d_ws, size_t ws_size,
                              hipStream_t stream)
{
    const float* h2   = (const float*)d_in[0];
    const float* Wenc = (const float*)d_in[1];
    const float* benc = (const float*)d_in[2];

    if (ws_size >= WSA_NEED) {
        // Path A: approx in workspace, output written directly
        char* wsb = (char*)d_ws;
        u16* Wb     = (u16*)(wsb + WSA_WB);
        u16* Ab     = (u16*)(wsb + WSA_AB);
        u16* approx = (u16*)(wsb + WSA_APX);
        float* Z = (float*)d_out;

        convert_bf16<<<2048, 256, 0, stream>>>(Wenc, h2, Wb, Ab);
        gemm8<<<2048, 512, 0, stream>>>(Ab, Wb, benc, approx, Z);   // also zeros Z
        select_rescore_final<<<NUNIT, 256, 0, stream>>>(approx, h2, Wenc, benc,
                                                        nullptr, nullptr, Z);
    } else {
        // Path B (proven R4 structure): approx inside d_out, pairs in d_ws
        char* ob = (char*)d_out;
        u16* approx = (u16*)ob;
        u16* Wb = (u16*)(ob + WB_OFF);
        u16* Ab = (u16*)(ob + AB_OFF);
        float* pv = (float*)d_ws;
        int*   pc = (int*)((char*)d_ws + (size_t)NROWS * NPAIR * 4);

        convert_bf16<<<2048, 256, 0, stream>>>(Wenc, h2, Wb, Ab);
        gemm8<<<2048, 512, 0, stream>>>(Ab, Wb, benc, approx, nullptr);
        select_rescore_final<<<NUNIT, 256, 0, stream>>>(approx, h2, Wenc, benc,
                                                        pv, pc, nullptr);
        zero_scatter<<<NROWS, 256, 0, stream>>>(pv, pc, (float*)d_out);
    }
}